// Round 2
// baseline (584.262 us; speedup 1.0000x reference)
//
#include <hip/hip_runtime.h>

#define TOWERS 4
#define F_IN 16
#define PRE_IN 32      // 2*F_IN
#define POST_IN 208    // F_IN*13
#define F_OUT 32
#define OUT_DIM 128
#define NB 32          // nodes per block in post kernel
#define AVG_LOG_DEG 2.8332133440562162f

// ---------------- CSR build ----------------

__global__ void k_init(int* __restrict__ deg, int* __restrict__ cursor, int n) {
    int i = blockIdx.x * 256 + threadIdx.x;
    if (i < n) { deg[i] = 0; cursor[i] = 0; }
}

__global__ void k_count(const int* __restrict__ recv, int* __restrict__ deg, int e) {
    int i = blockIdx.x * 256 + threadIdx.x;
    if (i < e) atomicAdd(&deg[recv[i]], 1);
}

__global__ void k_scan_block(const int* __restrict__ deg, int* __restrict__ offs,
                             int* __restrict__ bsum, int n) {
    __shared__ int s[256];
    int tid = threadIdx.x;
    int i = blockIdx.x * 256 + tid;
    int v = (i < n) ? deg[i] : 0;
    s[tid] = v;
    __syncthreads();
    #pragma unroll
    for (int off = 1; off < 256; off <<= 1) {
        int t = (tid >= off) ? s[tid - off] : 0;
        __syncthreads();
        s[tid] += t;
        __syncthreads();
    }
    if (i < n) offs[i] = s[tid] - v;     // exclusive
    if (tid == 255) bsum[blockIdx.x] = s[255];
}

__global__ void k_scan_bsum(int* __restrict__ bsum, int nb) {
    __shared__ int s[256];
    int tid = threadIdx.x;
    int v = (tid < nb) ? bsum[tid] : 0;
    s[tid] = v;
    __syncthreads();
    #pragma unroll
    for (int off = 1; off < 256; off <<= 1) {
        int t = (tid >= off) ? s[tid - off] : 0;
        __syncthreads();
        s[tid] += t;
        __syncthreads();
    }
    bsum[tid] = s[tid] - v;              // exclusive
}

__global__ void k_add_carry(int* __restrict__ offs, const int* __restrict__ bsum, int n) {
    int i = blockIdx.x * 256 + threadIdx.x;
    if (i < n) offs[i] += bsum[i >> 8];
}

__global__ void k_scatter(const int* __restrict__ send, const int* __restrict__ recv,
                          const int* __restrict__ offs, int* __restrict__ cursor,
                          int* __restrict__ src_sorted, int e) {
    int i = blockIdx.x * 256 + threadIdx.x;
    if (i < e) {
        int r = recv[i];
        int p = offs[r] + atomicAdd(&cursor[r], 1);
        src_sorted[p] = send[i];
    }
}

// ---------------- per-node aggregation (one wave per node) ----------------
// lane l handles message component (tower t = l>>4, feature f = l&15).
// msg[t][f] = pre_b[t][f] + sum_k x_i[t][k]*W[t][k][f] + sum_k x_j[t][k]*W[t][16+k][f]
// x_j (receiver) part is loop-invariant per node and hoisted into hjw.

__global__ __launch_bounds__(256) void k_aggregate(
    const float* __restrict__ nodes,
    const float* __restrict__ pre_w,
    const float* __restrict__ pre_b,
    const int* __restrict__ deg, const int* __restrict__ offs,
    const int* __restrict__ src_sorted,
    float* __restrict__ agg, int n)
{
    int lane = threadIdx.x & 63;
    int node = blockIdx.x * 4 + (threadIdx.x >> 6);
    if (node >= n) return;
    int t = lane >> 4, f = lane & 15;

    // per-lane weight column: w[k] = pre_w[t][k][f]
    float w[PRE_IN];
    #pragma unroll
    for (int k = 0; k < PRE_IN; ++k)
        w[k] = pre_w[(t * PRE_IN + k) * F_IN + f];

    // hoisted x_j (receiver = this node) contribution + bias
    const float4* xj = reinterpret_cast<const float4*>(nodes + (size_t)node * 64 + t * 16);
    float4 j0 = xj[0], j1 = xj[1], j2 = xj[2], j3 = xj[3];
    float hj[16] = {j0.x, j0.y, j0.z, j0.w, j1.x, j1.y, j1.z, j1.w,
                    j2.x, j2.y, j2.z, j2.w, j3.x, j3.y, j3.z, j3.w};
    float hjw = pre_b[t * F_IN + f];
    #pragma unroll
    for (int q = 0; q < 16; ++q)
        hjw = fmaf(hj[q], w[16 + q], hjw);

    int d = deg[node];
    int o = offs[node];
    float s = 0.f, s2 = 0.f, mx = -INFINITY, mn = INFINITY;
    for (int e = 0; e < d; ++e) {
        int sidx = src_sorted[o + e];
        const float4* xs = reinterpret_cast<const float4*>(nodes + (size_t)sidx * 64 + t * 16);
        float4 a0 = xs[0], a1 = xs[1], a2 = xs[2], a3 = xs[3];
        float ah[16] = {a0.x, a0.y, a0.z, a0.w, a1.x, a1.y, a1.z, a1.w,
                        a2.x, a2.y, a2.z, a2.w, a3.x, a3.y, a3.z, a3.w};
        float m = hjw;
        #pragma unroll
        for (int q = 0; q < 16; ++q)
            m = fmaf(ah[q], w[q], m);
        s += m;
        s2 = fmaf(m, m, s2);
        mx = fmaxf(mx, m);
        mn = fminf(mn, m);
    }

    float dc = fmaxf((float)d, 1.f);
    float inv = 1.f / dc;
    float mean = s * inv;
    float var = fmaf(-mean, mean, s2 * inv);
    float sd = sqrtf(fmaxf(var, 0.f) + 1e-5f);
    if (d == 0) { mx = 0.f; mn = 0.f; }

    // layout: [node][t*64 + stat*16 + f]  (matches concat([mean,std,mx,mn],-1))
    float* ag = agg + (size_t)node * 256 + t * 64 + f;
    ag[0]  = mean;
    ag[16] = sd;
    ag[32] = mx;
    ag[48] = mn;
}

// ---------------- post-MLP + final linear (32 nodes per block) ----------------

__global__ __launch_bounds__(256) void k_post(
    const float* __restrict__ nodes,
    const float* __restrict__ agg,
    const int* __restrict__ deg,
    const float* __restrict__ post_w,
    const float* __restrict__ post_b,
    const float* __restrict__ lin_w,
    const float* __restrict__ lin_b,
    float* __restrict__ out, int n)
{
    __shared__ float vec[NB][212];      // 212 = 208 padded (bank stagger)
    __shared__ float flat[NB][128];
    __shared__ float s_amp[NB], s_att[NB];
    int tid = threadIdx.x;
    int n0 = blockIdx.x * NB;

    if (tid < NB) {
        int gn = n0 + tid;
        float dc = 1.f;
        if (gn < n) dc = fmaxf((float)deg[gn], 1.f);
        float ld = logf(dc + 1.f);
        s_amp[tid] = ld * (1.0f / AVG_LOG_DEG);
        s_att[tid] = AVG_LOG_DEG / ld;
    }
    __syncthreads();

    for (int t = 0; t < TOWERS; ++t) {
        // build [x(16) | agg(64) | agg*amp(64) | agg*att(64)] per node for tower t
        for (int idx = tid; idx < NB * POST_IN; idx += 256) {
            int nn = idx / POST_IN;
            int j = idx - nn * POST_IN;
            int gn = n0 + nn;
            float v = 0.f;
            if (gn < n) {
                if (j < 16)       v = nodes[(size_t)gn * 64 + t * 16 + j];
                else if (j < 80)  v = agg[(size_t)gn * 256 + t * 64 + (j - 16)];
                else if (j < 144) v = agg[(size_t)gn * 256 + t * 64 + (j - 80)] * s_amp[nn];
                else              v = agg[(size_t)gn * 256 + t * 64 + (j - 144)] * s_att[nn];
            }
            vec[nn][j] = v;
        }
        __syncthreads();

        // [NB x 208] x [208 x 32] for tower t -> flat[:, t*32 : t*32+32]
        {
            int o = (tid & 7) * 4;   // output col base (0..28)
            int nn = tid >> 3;       // node (0..31)
            float a0 = 0.f, a1 = 0.f, a2 = 0.f, a3 = 0.f;
            for (int fq = 0; fq < POST_IN; fq += 4) {
                float4 hv = *reinterpret_cast<const float4*>(&vec[nn][fq]);
                #pragma unroll
                for (int u = 0; u < 4; ++u) {
                    float h = (&hv.x)[u];
                    float4 wp = *reinterpret_cast<const float4*>(
                        post_w + ((size_t)t * POST_IN + fq + u) * F_OUT + o);
                    a0 = fmaf(h, wp.x, a0);
                    a1 = fmaf(h, wp.y, a1);
                    a2 = fmaf(h, wp.z, a2);
                    a3 = fmaf(h, wp.w, a3);
                }
            }
            int ob = t * F_OUT + o;
            flat[nn][ob + 0] = a0 + post_b[t * F_OUT + o + 0];
            flat[nn][ob + 1] = a1 + post_b[t * F_OUT + o + 1];
            flat[nn][ob + 2] = a2 + post_b[t * F_OUT + o + 2];
            flat[nn][ob + 3] = a3 + post_b[t * F_OUT + o + 3];
        }
        __syncthreads();
    }

    // final: [NB x 128] x [128 x 128]
    int c = (tid & 31) * 4;          // col base
    int nb4 = (tid >> 5) * 4;        // node base (4 nodes per thread)
    float acc[4][4];
    #pragma unroll
    for (int i = 0; i < 4; ++i)
        #pragma unroll
        for (int q = 0; q < 4; ++q) acc[i][q] = 0.f;

    for (int kq = 0; kq < 128; kq += 4) {
        float4 fv[4];
        #pragma unroll
        for (int i = 0; i < 4; ++i)
            fv[i] = *reinterpret_cast<const float4*>(&flat[nb4 + i][kq]);
        #pragma unroll
        for (int u = 0; u < 4; ++u) {
            float4 wp = *reinterpret_cast<const float4*>(lin_w + (size_t)(kq + u) * 128 + c);
            #pragma unroll
            for (int i = 0; i < 4; ++i) {
                float h = (&fv[i].x)[u];
                acc[i][0] = fmaf(h, wp.x, acc[i][0]);
                acc[i][1] = fmaf(h, wp.y, acc[i][1]);
                acc[i][2] = fmaf(h, wp.z, acc[i][2]);
                acc[i][3] = fmaf(h, wp.w, acc[i][3]);
            }
        }
    }

    float b0 = lin_b[c + 0];
    float b1 = lin_b[c + 1];
    float b2 = lin_b[c + 2];
    float b3 = lin_b[c + 3];
    #pragma unroll
    for (int i = 0; i < 4; ++i) {
        int gn = n0 + nb4 + i;
        if (gn < n) {
            float* po = out + (size_t)gn * OUT_DIM + c;
            po[0] = acc[i][0] + b0;
            po[1] = acc[i][1] + b1;
            po[2] = acc[i][2] + b2;
            po[3] = acc[i][3] + b3;
        }
    }
}

extern "C" void kernel_launch(void* const* d_in, const int* in_sizes, int n_in,
                              void* d_out, int out_size, void* d_ws, size_t ws_size,
                              hipStream_t stream)
{
    const float* nodes  = (const float*)d_in[0];
    const int*   send   = (const int*)d_in[1];
    const int*   recv   = (const int*)d_in[2];
    const float* pre_w  = (const float*)d_in[3];
    const float* pre_b  = (const float*)d_in[4];
    const float* post_w = (const float*)d_in[5];
    const float* post_b = (const float*)d_in[6];
    const float* lin_w  = (const float*)d_in[7];
    const float* lin_b  = (const float*)d_in[8];
    float* out = (float*)d_out;

    int N = in_sizes[0] / 64;
    int E = in_sizes[1];
    int Npad = (N + 255) & ~255;
    int Epad = (E + 255) & ~255;

    int* deg    = (int*)d_ws;          // Npad
    int* offs   = deg + Npad;          // Npad
    int* cursor = offs + Npad;         // Npad
    int* bsum   = cursor + Npad;       // 1024
    int* srcs   = bsum + 1024;         // Epad
    float* agg  = (float*)(srcs + Epad); // N*256 floats

    int nbN = (N + 255) / 256;
    int nbE = (E + 255) / 256;

    k_init      <<<nbN, 256, 0, stream>>>(deg, cursor, N);
    k_count     <<<nbE, 256, 0, stream>>>(recv, deg, E);
    k_scan_block<<<nbN, 256, 0, stream>>>(deg, offs, bsum, N);
    k_scan_bsum <<<1,   256, 0, stream>>>(bsum, nbN);
    k_add_carry <<<nbN, 256, 0, stream>>>(offs, bsum, N);
    k_scatter   <<<nbE, 256, 0, stream>>>(send, recv, offs, cursor, srcs, E);
    k_aggregate <<<(N + 3) / 4, 256, 0, stream>>>(nodes, pre_w, pre_b, deg, offs, srcs, agg, N);
    k_post      <<<(N + NB - 1) / NB, 256, 0, stream>>>(nodes, agg, deg, post_w, post_b, lin_w, lin_b, out, N);
}